// Round 11
// baseline (260.796 us; speedup 1.0000x reference)
//
#include <hip/hip_runtime.h>
#include <hip/hip_bf16.h>

// GCN 3-layer. Linearity: segsum(h[src]) @ W == segsum((h@W)[src]).
// R11: agg reverted to R9 exact (unroll-4; R10's unroll-8 cost occupancy).
//      mm-layer-0 FUSED into bin_count's grid (independent of CSR chain) ->
//      its ~15us runs concurrently with the histogram. prep_w eliminated:
//      every mm kernel inline-transposes its f32 W into LDS (bf16).
//      bin_scatter tile 8192->4096 (391 blocks, fills the chip).
// Pipeline:
//   k_count_mm0: blocks[0,256)=dst histogram, blocks[256,..)=mm0 (features@W0)
//   bin_scan -> bin_scatter -> csr_build
//   bufB = relu(agg(bufA)+b0)    (agg128_bf16)
//   bufA = bufB @ W1             (mm128_w, inline W transpose)
//   bufB = relu(agg(bufA)+b1)    (agg128_bf16)
//   bufC = bufB @ W2             (mm40_w, inline W transpose)
//   out  = agg40(bufC) + b2      (agg40_bf16)

#define FEAT 128
#define BIN_SHIFT 8
#define MAX_BINS 512
#define SCAT_TILE 4096
#define COUNT_BLOCKS 256

typedef __attribute__((ext_vector_type(8))) short bf16x8_t;
typedef __attribute__((ext_vector_type(4))) float f32x4_t;

// ---------------- helpers ----------------

__device__ __forceinline__ void bf16x8_add(float* a, uint4 v) {
    a[0] += __uint_as_float(v.x << 16);
    a[1] += __uint_as_float(v.x & 0xffff0000u);
    a[2] += __uint_as_float(v.y << 16);
    a[3] += __uint_as_float(v.y & 0xffff0000u);
    a[4] += __uint_as_float(v.z << 16);
    a[5] += __uint_as_float(v.z & 0xffff0000u);
    a[6] += __uint_as_float(v.w << 16);
    a[7] += __uint_as_float(v.w & 0xffff0000u);
}

__device__ __forceinline__ unsigned pack_bf16(float a, float b) {
    union { __hip_bfloat162 h; unsigned u; } c;
    c.h.x = __float2bfloat16(a);
    c.h.y = __float2bfloat16(b);
    return c.u;
}

__device__ __forceinline__ unsigned short f2bf(float x) {
    union { __hip_bfloat16 h; unsigned short s; } c;
    c.h = __float2bfloat16(x);
    return c.s;
}

// ------- mm128 body: C[rows row0..+128](bf16) = A @ W(f32 [k][n], inline-T) ----

template <bool AF32>
__device__ __forceinline__ void mm128_body(unsigned char* smem, const void* Av,
                                           const float* __restrict__ W,
                                           unsigned* __restrict__ C, int n,
                                           int row0, int t) {
    // inline W transpose into LDS: smem[nn*272 + k*2] = bf16(W[k*128+nn])
    for (int i = t; i < 16384; i += 256) {
        int k = i >> 7, nn = i & 127;
        *(unsigned short*)(smem + nn * 272 + k * 2) = f2bf(W[i]);
    }

    const int w = t >> 6;
    const int l = t & 63;
    const int rl = l & 15;
    const int g = l >> 4;

    bf16x8_t a[2][4];
#pragma unroll
    for (int rt = 0; rt < 2; ++rt) {
        const int row = row0 + w * 32 + rt * 16 + rl;
        const bool ok = row < n;
#pragma unroll
        for (int kc = 0; kc < 4; ++kc) {
            union { uint4 u; bf16x8_t h; } pk;
            pk.u = make_uint4(0, 0, 0, 0);
            if (AF32) {
                if (ok) {
                    const float* ap = (const float*)Av + (size_t)row * 128 + kc * 32 + g * 8;
                    float4 lo = *(const float4*)ap;
                    float4 hi = *(const float4*)(ap + 4);
                    pk.u = make_uint4(pack_bf16(lo.x, lo.y), pack_bf16(lo.z, lo.w),
                                      pack_bf16(hi.x, hi.y), pack_bf16(hi.z, hi.w));
                }
            } else {
                if (ok)
                    pk.u = *(const uint4*)((const unsigned*)Av + (size_t)row * 64 + kc * 16 + g * 4);
            }
            a[rt][kc] = pk.h;
        }
    }
    __syncthreads();

    f32x4_t acc[2][8];
#pragma unroll
    for (int rt = 0; rt < 2; ++rt)
#pragma unroll
        for (int ct = 0; ct < 8; ++ct)
            acc[rt][ct] = (f32x4_t){0.f, 0.f, 0.f, 0.f};

#pragma unroll
    for (int ct = 0; ct < 8; ++ct) {
#pragma unroll
        for (int kc = 0; kc < 4; ++kc) {
            bf16x8_t b = *(const bf16x8_t*)(smem + (ct * 16 + rl) * 272 + kc * 64 + g * 16);
            acc[0][ct] = __builtin_amdgcn_mfma_f32_16x16x32_bf16(a[0][kc], b, acc[0][ct], 0, 0, 0);
            acc[1][ct] = __builtin_amdgcn_mfma_f32_16x16x32_bf16(a[1][kc], b, acc[1][ct], 0, 0, 0);
        }
    }
    __syncthreads();

#pragma unroll
    for (int rt = 0; rt < 2; ++rt)
#pragma unroll
        for (int ct = 0; ct < 8; ++ct)
#pragma unroll
            for (int r = 0; r < 4; ++r) {
                int lr = w * 32 + rt * 16 + g * 4 + r;
                int col = ct * 16 + rl;
                *(unsigned short*)(smem + lr * 272 + col * 2) = f2bf(acc[rt][ct][r]);
            }
    __syncthreads();

    for (int i = t; i < 2048; i += 256) {
        int r = i >> 4, j = i & 15;
        int row = row0 + r;
        if (row < n)
            *(uint4*)(C + (size_t)row * 64 + j * 4) = *(const uint4*)(smem + r * 272 + j * 16);
    }
}

// -------- k_count_mm0: blocks[0,256) dst-histogram; rest = mm0 ---------------

__global__ __launch_bounds__(256) void k_count_mm0(const int* __restrict__ dst,
                                                   int* __restrict__ bin_counts,
                                                   int n_edges, int nb,
                                                   const float* __restrict__ features,
                                                   const float* __restrict__ W0,
                                                   unsigned* __restrict__ bufA,
                                                   int n_nodes) {
    __shared__ __align__(16) unsigned char smem[128 * 272];  // 34 KB (union)
    const int t = threadIdx.x;

    if (blockIdx.x < COUNT_BLOCKS) {
        int* hist = (int*)smem;
        for (int i = t; i < nb; i += 256) hist[i] = 0;
        __syncthreads();
        const int n4 = n_edges >> 2;
        for (int i = blockIdx.x * 256 + t; i < n4; i += COUNT_BLOCKS * 256) {
            int4 d = ((const int4*)dst)[i];
            atomicAdd(&hist[d.x >> BIN_SHIFT], 1);
            atomicAdd(&hist[d.y >> BIN_SHIFT], 1);
            atomicAdd(&hist[d.z >> BIN_SHIFT], 1);
            atomicAdd(&hist[d.w >> BIN_SHIFT], 1);
        }
        if (blockIdx.x == 0 && t < (n_edges & 3))
            atomicAdd(&hist[dst[n4 * 4 + t] >> BIN_SHIFT], 1);
        __syncthreads();
        for (int i = t; i < nb; i += 256) {
            int h = hist[i];
            if (h) atomicAdd(&bin_counts[i], h);
        }
        return;
    }

    const int row0 = (blockIdx.x - COUNT_BLOCKS) * 128;
    mm128_body<true>(smem, features, W0, bufA, n_nodes, row0, t);
}

// ---------------- mm128_w: layer-1 matmul (bf16 A, inline W transpose) -------

__global__ __launch_bounds__(256) void mm128_w(const unsigned* __restrict__ Ab,
                                               const float* __restrict__ W,
                                               unsigned* __restrict__ C, int n) {
    __shared__ __align__(16) unsigned char smem[128 * 272];
    mm128_body<false>(smem, Ab, W, C, n, blockIdx.x * 128, threadIdx.x);
}

// ---------------- CSR build (scan/scatter/build) ----------------

__global__ __launch_bounds__(512) void bin_scan(const int* __restrict__ bin_counts,
                                                int* __restrict__ bin_offsets,
                                                int* __restrict__ bin_cursor,
                                                int* __restrict__ offsets,
                                                int nb, int n_nodes, int n_edges) {
    __shared__ int sc[512];
    const int t = threadIdx.x;
    const int v = (t < nb) ? bin_counts[t] : 0;
    sc[t] = v;
    __syncthreads();
    for (int off = 1; off < 512; off <<= 1) {
        int u = (t >= off) ? sc[t - off] : 0;
        __syncthreads();
        sc[t] += u;
        __syncthreads();
    }
    if (t <= nb) {
        int e = (t < nb) ? (sc[t] - v) : n_edges;
        bin_offsets[t] = e;
        if (t < nb) bin_cursor[t] = e;
    }
    if (t == 0) offsets[n_nodes] = n_edges;
}

__global__ __launch_bounds__(256) void bin_scatter(const int* __restrict__ src,
                                                   const int* __restrict__ dst,
                                                   int* __restrict__ bin_cursor,
                                                   int* __restrict__ ebuf,
                                                   int n_edges, int nb) {
    __shared__ int hist[MAX_BINS];
    __shared__ int cur[MAX_BINS];
    const int t = threadIdx.x;
    const int lo = blockIdx.x * SCAT_TILE;
    const int hi = min(lo + SCAT_TILE, n_edges);
    for (int i = t; i < nb; i += 256) hist[i] = 0;
    __syncthreads();
    for (int i = lo + t; i < hi; i += 256) atomicAdd(&hist[dst[i] >> BIN_SHIFT], 1);
    __syncthreads();
    for (int i = t; i < nb; i += 256) {
        int h = hist[i];
        cur[i] = h ? atomicAdd(&bin_cursor[i], h) : 0;
    }
    __syncthreads();
    for (int i = lo + t; i < hi; i += 256) {
        int d = dst[i];
        int b = d >> BIN_SHIFT;
        int pos = atomicAdd(&cur[b], 1);
        ebuf[pos] = ((d & 255) << 24) | src[i];
    }
}

__global__ __launch_bounds__(256) void csr_build(const int* __restrict__ ebuf,
                                                 const int* __restrict__ bin_offsets,
                                                 int* __restrict__ offsets,
                                                 int* __restrict__ csr,
                                                 int n_nodes) {
    __shared__ int cnt[256];
    __shared__ int sc[256];
    __shared__ int cur[256];
    const int b = blockIdx.x;
    const int t = threadIdx.x;
    const int lo = bin_offsets[b];
    const int hi = bin_offsets[b + 1];
    cnt[t] = 0;
    __syncthreads();
    for (int e = lo + t; e < hi; e += 256)
        atomicAdd(&cnt[((unsigned)ebuf[e]) >> 24], 1);
    __syncthreads();
    const int x = cnt[t];
    sc[t] = x;
    __syncthreads();
    for (int off = 1; off < 256; off <<= 1) {
        int u = (t >= off) ? sc[t - off] : 0;
        __syncthreads();
        sc[t] += u;
        __syncthreads();
    }
    const int start = lo + sc[t] - x;
    cur[t] = start;
    const int node = (b << BIN_SHIFT) + t;
    if (node < n_nodes) offsets[node] = start;
    __syncthreads();
    for (int e = lo + t; e < hi; e += 256) {
        int p = ebuf[e];
        int dl = ((unsigned)p) >> 24;
        int pos = atomicAdd(&cur[dl], 1);
        csr[pos] = p & 0x00FFFFFF;
    }
}

// ------- agg128_bf16 (R9 exact): 16 lanes/node, 16 nodes/block, unroll-4 -----

__global__ __launch_bounds__(256) void agg128_bf16(const unsigned* __restrict__ X,
                                                   const int* __restrict__ offsets,
                                                   const int* __restrict__ csr_src,
                                                   const float* __restrict__ bias,
                                                   unsigned* __restrict__ Yb, int n) {
    const int t = threadIdx.x;
    const int g = t >> 4;
    const int lane = t & 15;
    const int node = blockIdx.x * 16 + g;
    if (node >= n) return;
    const int e0 = offsets[node];
    const int e1 = offsets[node + 1];
    const int cu = lane * 4;
    float acc[8] = {0.f, 0.f, 0.f, 0.f, 0.f, 0.f, 0.f, 0.f};
    int e = e0;
    for (; e + 3 < e1; e += 4) {
        int s0 = csr_src[e];
        int s1 = csr_src[e + 1];
        int s2 = csr_src[e + 2];
        int s3 = csr_src[e + 3];
        uint4 v0 = *(const uint4*)(X + (size_t)s0 * 64 + cu);
        uint4 v1 = *(const uint4*)(X + (size_t)s1 * 64 + cu);
        uint4 v2 = *(const uint4*)(X + (size_t)s2 * 64 + cu);
        uint4 v3 = *(const uint4*)(X + (size_t)s3 * 64 + cu);
        bf16x8_add(acc, v0);
        bf16x8_add(acc, v1);
        bf16x8_add(acc, v2);
        bf16x8_add(acc, v3);
    }
    for (; e < e1; ++e) {
        int s0 = csr_src[e];
        uint4 v0 = *(const uint4*)(X + (size_t)s0 * 64 + cu);
        bf16x8_add(acc, v0);
    }
    float4 b0 = *(const float4*)(bias + lane * 8);
    float4 b1 = *(const float4*)(bias + lane * 8 + 4);
    acc[0] = fmaxf(acc[0] + b0.x, 0.f);
    acc[1] = fmaxf(acc[1] + b0.y, 0.f);
    acc[2] = fmaxf(acc[2] + b0.z, 0.f);
    acc[3] = fmaxf(acc[3] + b0.w, 0.f);
    acc[4] = fmaxf(acc[4] + b1.x, 0.f);
    acc[5] = fmaxf(acc[5] + b1.y, 0.f);
    acc[6] = fmaxf(acc[6] + b1.z, 0.f);
    acc[7] = fmaxf(acc[7] + b1.w, 0.f);
    *(uint4*)(Yb + (size_t)node * 64 + cu) =
        make_uint4(pack_bf16(acc[0], acc[1]), pack_bf16(acc[2], acc[3]),
                   pack_bf16(acc[4], acc[5]), pack_bf16(acc[6], acc[7]));
}

// ------- agg40_bf16 (R9 exact): 8 lanes/node (5 active), 32 nodes/block ------

__global__ __launch_bounds__(256) void agg40_bf16(const unsigned* __restrict__ X,
                                                  const int* __restrict__ offsets,
                                                  const int* __restrict__ csr_src,
                                                  const float* __restrict__ bias,
                                                  float* __restrict__ Y, int n) {
    const int t = threadIdx.x;
    const int g = t >> 3;
    const int lane = t & 7;
    const int node = blockIdx.x * 32 + g;
    if (node >= n) return;
    const int e0 = offsets[node];
    const int e1 = offsets[node + 1];
    const bool active = lane < 5;
    const int cu = lane * 4;
    float acc[8] = {0.f, 0.f, 0.f, 0.f, 0.f, 0.f, 0.f, 0.f};
    int e = e0;
    for (; e + 3 < e1; e += 4) {
        int s0 = csr_src[e];
        int s1 = csr_src[e + 1];
        int s2 = csr_src[e + 2];
        int s3 = csr_src[e + 3];
        if (active) {
            uint4 v0 = *(const uint4*)(X + (size_t)s0 * 20 + cu);
            uint4 v1 = *(const uint4*)(X + (size_t)s1 * 20 + cu);
            uint4 v2 = *(const uint4*)(X + (size_t)s2 * 20 + cu);
            uint4 v3 = *(const uint4*)(X + (size_t)s3 * 20 + cu);
            bf16x8_add(acc, v0);
            bf16x8_add(acc, v1);
            bf16x8_add(acc, v2);
            bf16x8_add(acc, v3);
        }
    }
    for (; e < e1; ++e) {
        int s0 = csr_src[e];
        if (active) {
            uint4 v0 = *(const uint4*)(X + (size_t)s0 * 20 + cu);
            bf16x8_add(acc, v0);
        }
    }
    if (active) {
        float4 b0 = *(const float4*)(bias + lane * 8);
        float4 b1 = *(const float4*)(bias + lane * 8 + 4);
        float* yp = Y + (size_t)node * 40 + lane * 8;
        *(float4*)yp = make_float4(acc[0] + b0.x, acc[1] + b0.y,
                                   acc[2] + b0.z, acc[3] + b0.w);
        *(float4*)(yp + 4) = make_float4(acc[4] + b1.x, acc[5] + b1.y,
                                         acc[6] + b1.z, acc[7] + b1.w);
    }
}

// ------- mm40_w: C[N,40](bf16) = A[N,128](bf16) @ W2[128,40](f32, inline-T) --

__global__ __launch_bounds__(256) void mm40_w(const unsigned* __restrict__ Ab,
                                              const float* __restrict__ W2,
                                              unsigned* __restrict__ C, int n) {
    __shared__ __align__(16) unsigned char Wlds[48 * 272];   // 13 KB
    __shared__ __align__(16) float bounce[64 * 52];          // 13.3 KB
    const int t = threadIdx.x;
    const int w = t >> 6;
    const int l = t & 63;
    const int rl = l & 15;
    const int g = l >> 4;
    const int row0 = blockIdx.x * 64;

    // inline W2 transpose: Wlds[nn*272 + k*2] = bf16(W2[k*40+nn]), rows 40..47 = 0
    for (int i = t; i < 6144; i += 256) {
        int nn = i >> 7, k = i & 127;
        float v = (nn < 40) ? W2[k * 40 + nn] : 0.f;
        *(unsigned short*)(Wlds + nn * 272 + k * 2) = f2bf(v);
    }

    bf16x8_t a[4];
    {
        const int row = row0 + w * 16 + rl;
        const bool ok = row < n;
#pragma unroll
        for (int kc = 0; kc < 4; ++kc) {
            union { uint4 u; bf16x8_t h; } pk;
            pk.u = make_uint4(0, 0, 0, 0);
            if (ok)
                pk.u = *(const uint4*)(Ab + (size_t)row * 64 + kc * 16 + g * 4);
            a[kc] = pk.h;
        }
    }
    __syncthreads();

    f32x4_t acc[3];
#pragma unroll
    for (int ct = 0; ct < 3; ++ct) acc[ct] = (f32x4_t){0.f, 0.f, 0.f, 0.f};

#pragma unroll
    for (int kc = 0; kc < 4; ++kc) {
#pragma unroll
        for (int ct = 0; ct < 3; ++ct) {
            bf16x8_t b = *(const bf16x8_t*)(Wlds + (ct * 16 + rl) * 272 + kc * 64 + g * 16);
            acc[ct] = __builtin_amdgcn_mfma_f32_16x16x32_bf16(a[kc], b, acc[ct], 0, 0, 0);
        }
    }

#pragma unroll
    for (int ct = 0; ct < 3; ++ct)
#pragma unroll
        for (int r = 0; r < 4; ++r)
            bounce[(w * 16 + g * 4 + r) * 52 + ct * 16 + rl] = acc[ct][r];
    __syncthreads();

    for (int i = t; i < 1280; i += 256) {  // 64 rows x 20 u32
        int r = i / 20, j = i % 20;
        int row = row0 + r;
        if (row < n)
            C[(size_t)row * 20 + j] =
                pack_bf16(bounce[r * 52 + j * 2], bounce[r * 52 + j * 2 + 1]);
    }
}

// ---------------- launch ----------------

extern "C" void kernel_launch(void* const* d_in, const int* in_sizes, int n_in,
                              void* d_out, int out_size, void* d_ws, size_t ws_size,
                              hipStream_t stream) {
    const float* features = (const float*)d_in[0];
    const int* src = (const int*)d_in[1];
    const int* dst = (const int*)d_in[2];
    const float* W0 = (const float*)d_in[3];
    const float* b0 = (const float*)d_in[4];
    const float* W1 = (const float*)d_in[5];
    const float* b1 = (const float*)d_in[6];
    const float* W2 = (const float*)d_in[7];
    const float* b2 = (const float*)d_in[8];
    float* out = (float*)d_out;

    const int n_nodes = in_sizes[0] / FEAT;
    const int n_edges = in_sizes[1];
    const int nb = (n_nodes + 255) >> BIN_SHIFT;

    char* p = (char*)d_ws;
    auto alloc = [&](size_t bytes) {
        char* q = p;
        p += (bytes + 255) & ~(size_t)255;
        return q;
    };
    unsigned* bufA  = (unsigned*)alloc((size_t)n_nodes * FEAT * 2);  // bf16 [N,128]
    unsigned* bufB  = (unsigned*)alloc((size_t)n_nodes * FEAT * 2);  // bf16 [N,128]
    int* offsets    = (int*)alloc((size_t)(n_nodes + 1) * 4);
    int* csr        = (int*)alloc((size_t)n_edges * 4);
    int* ebuf       = (int*)alloc((size_t)n_edges * 4);
    int* bin_counts = (int*)alloc(MAX_BINS * 4);
    int* bin_offs   = (int*)alloc((MAX_BINS + 1) * 4);
    int* bin_cursor = (int*)alloc(MAX_BINS * 4);
    unsigned* bufC  = bufA;  // alias: bf16 [N,40] fits in bufA's region (bufA dead)

    const int mmf_grid = (n_nodes + 127) / 128;
    const int mm40_grid = (n_nodes + 63) / 64;
    const int agg_grid = (n_nodes + 15) / 16;
    const int agg40_grid = (n_nodes + 31) / 32;

    // CSR build; layer-0 matmul rides along in k_count_mm0's grid
    hipMemsetAsync(bin_counts, 0, MAX_BINS * 4, stream);
    k_count_mm0<<<COUNT_BLOCKS + mmf_grid, 256, 0, stream>>>(
        dst, bin_counts, n_edges, nb, features, W0, bufA, n_nodes);
    bin_scan<<<1, 512, 0, stream>>>(bin_counts, bin_offs, bin_cursor, offsets,
                                    nb, n_nodes, n_edges);
    bin_scatter<<<(n_edges + SCAT_TILE - 1) / SCAT_TILE, 256, 0, stream>>>(
        src, dst, bin_cursor, ebuf, n_edges, nb);
    csr_build<<<nb, 256, 0, stream>>>(ebuf, bin_offs, offsets, csr, n_nodes);

    // layer 0 agg
    agg128_bf16<<<agg_grid, 256, 0, stream>>>(bufA, offsets, csr, b0, bufB, n_nodes);
    // layer 1
    mm128_w<<<mmf_grid, 256, 0, stream>>>(bufB, W1, bufA, n_nodes);
    agg128_bf16<<<agg_grid, 256, 0, stream>>>(bufA, offsets, csr, b1, bufB, n_nodes);
    // layer 2: matmul-first (128->40), then aggregate + bias
    mm40_w<<<mm40_grid, 256, 0, stream>>>(bufB, W2, bufC, n_nodes);
    agg40_bf16<<<agg40_grid, 256, 0, stream>>>(bufC, offsets, csr, b2, out, n_nodes);
}